// Round 8
// baseline (436.561 us; speedup 1.0000x reference)
//
#include <hip/hip_runtime.h>
#include <hip/hip_cooperative_groups.h>
#include <cstdint>
#include <cstddef>

namespace cg = cooperative_groups;

#define BB 32
#define AA 8400
#define NBB 32
#define CC 80
#define TOPKN 10
#define MAXC 1536   // >= max inside-anchors per gt: 33^2+17^2+9^2 = 1459
#define CSTR 16     // cnt padding (ints) -> 64B/counter
#define GRID 1024
#define NTHR 256

// ===========================================================================
// Single cooperative kernel, 5 phases separated by grid.sync().
// Block mapping: b = bid>>5 (batch), xc = bid&31 (anchor chunk for P1/P3,
// gt j for P2 where g == bid). Eliminates 4 kernel boundaries of the prior
// 5-kernel pipeline and makes the total cost visible as one dispatch row.
// ===========================================================================
__global__ __launch_bounds__(NTHR, 4) void fused_kernel(
    const float* __restrict__ pred_scores, const float* __restrict__ pred_boxes,
    const float* __restrict__ anchor_points, const int* __restrict__ gt_labels,
    const float* __restrict__ gt_boxes, const int* __restrict__ gt_mask,
    float* __restrict__ out,
    unsigned long long* __restrict__ cand, int* __restrict__ cnt,
    int* __restrict__ posA, int* __restrict__ posI, int* __restrict__ acc,
    int* __restrict__ assign_ws, float* __restrict__ align_ws) {
  cg::grid_group gg = cg::this_grid();
  const int bid = blockIdx.x, t = threadIdx.x;
  const int lane = t & 63;
  const int b = bid >> 5;
  const int xc = bid & 31;

  __shared__ float sbox[NBB][4];
  __shared__ int scls[NBB];
  __shared__ int svalid[NBB];
  __shared__ unsigned long long s_key[NTHR][TOPKN];

  // ---- P0: zero cnt|posA|posI (contiguous 72KB starting at cnt) ----
  {
    const int nint4 = (NBB * BB * CSTR + 1024 + 1024) * 4 / 16;  // 4608
    const int i = bid * NTHR + t;
    if (i < nint4) reinterpret_cast<int4*>(cnt)[i] = make_int4(0, 0, 0, 0);
  }
  gg.sync();

  // ---- P1: compact candidates (wave-aggregated append); zero acc ----
  if (t < NBB) {
    const int g = b * NBB + t;
    sbox[t][0] = gt_boxes[g * 4 + 0];
    sbox[t][1] = gt_boxes[g * 4 + 1];
    sbox[t][2] = gt_boxes[g * 4 + 2];
    sbox[t][3] = gt_boxes[g * 4 + 3];
    scls[t] = gt_labels[g];
    svalid[t] = (gt_mask[g] != 0) ? 1 : 0;
  }
  __syncthreads();

  for (int it = 0; it < 2; ++it) {
    const int a = xc * NTHR + t + it * (32 * NTHR);
    const bool inr = (a < AA);
    float apx = 0.f, apy = 0.f, p0 = 0.f, p1 = 0.f, p2 = 0.f, p3 = 0.f;
    float a2 = 0.f;
    const float* srow = pred_scores + ((size_t)b * AA + (inr ? a : 0)) * CC;
    if (inr) {
      apx = anchor_points[a * 2 + 0];
      apy = anchor_points[a * 2 + 1];
      const float* pb = pred_boxes + ((size_t)b * AA + a) * 4;
      p0 = pb[0]; p1 = pb[1]; p2 = pb[2]; p3 = pb[3];
      a2 = (p2 - p0) * (p3 - p1);
      acc[b * AA + a] = 0;  // zero acc here (P2 atomicAdds it after sync)
    }
    for (int j = 0; j < NBB; j++) {
      bool hit = false;
      float align_v = 0.0f;
      if (inr && svalid[j]) {
        const float gx0 = sbox[j][0], gy0 = sbox[j][1];
        const float gx1 = sbox[j][2], gy1 = sbox[j][3];
        const float d = fminf(fminf(apx - gx0, apy - gy0),
                              fminf(gx1 - apx, gy1 - apy));
        if (d > 1e-8f) {
          const float iw = fmaxf(fminf(gx1, p2) - fmaxf(gx0, p0), 0.0f);
          const float ih = fmaxf(fminf(gy1, p3) - fmaxf(gy0, p1), 0.0f);
          const float inter = iw * ih;
          const float a1 = (gx1 - gx0) * (gy1 - gy0);
          const float iou = fmaxf(inter / (a1 + a2 - inter + 1e-10f), 0.0f);
          const float s = srow[scls[j]];
          const float i2 = iou * iou;
          align_v = s * i2 * i2 * i2;
          hit = true;
        }
      }
      const unsigned long long m = __ballot(hit);
      if (m == 0ull) continue;
      const int leader = (int)__ffsll((unsigned long long)m) - 1;
      int base = 0;
      if (lane == leader)
        base = atomicAdd(&cnt[(b * NBB + j) * CSTR], (int)__popcll(m));
      base = __shfl(base, leader);
      if (hit) {
        const int rank = (int)__popcll(m & ((1ull << lane) - 1ull));
        const int pos = base + rank;
        if (pos < MAXC) {
          // descending u64 == descending align, tie -> smaller anchor idx
          const unsigned long long key =
              ((unsigned long long)__float_as_uint(align_v) << 32) |
              (unsigned int)(AA - a);
          cand[(size_t)(b * NBB + j) * MAXC + pos] = key;
        }
      }
    }
  }
  gg.sync();

  // ---- P2: top-10 per gt (g == bid); scatter (1<<16)|j into acc ----
  {
    const int g = bid;
    const int n = min(cnt[g * CSTR], MAXC);

    unsigned long long tk[TOPKN];
#pragma unroll
    for (int k = 0; k < TOPKN; k++) tk[k] = 0ull;

    for (int i = t; i < n; i += NTHR) {
      const unsigned long long key = cand[(size_t)g * MAXC + i];
      if (key > tk[TOPKN - 1]) {
        tk[TOPKN - 1] = key;
#pragma unroll
        for (int k = TOPKN - 1; k > 0; k--) {
          if (tk[k] > tk[k - 1]) {
            unsigned long long tmp = tk[k]; tk[k] = tk[k - 1]; tk[k - 1] = tmp;
          }
        }
      }
    }
#pragma unroll
    for (int k = 0; k < TOPKN; k++) s_key[t][k] = tk[k];
    __syncthreads();

    for (int stride = NTHR / 2; stride >= 1; stride >>= 1) {
      if (t < stride) {
        unsigned long long mk[TOPKN];
        int p = 0, q = 0;
#pragma unroll
        for (int k = 0; k < TOPKN; k++) {
          const unsigned long long k1 = s_key[t][p], k2 = s_key[t + stride][q];
          if (k1 >= k2) { mk[k] = k1; p++; } else { mk[k] = k2; q++; }
        }
#pragma unroll
        for (int k = 0; k < TOPKN; k++) s_key[t][k] = mk[k];
      }
      __syncthreads();
    }

    if (t < TOPKN) {
      const unsigned long long key = s_key[0][t];
      if (key != 0ull) {
        const int a = AA - (int)(key & 0xffffffffu);
        atomicAdd(&acc[(g >> 5) * AA + a], 65536 + (g & 31));
      }
    }
  }
  gg.sync();

  // ---- P3: resolve conflicts; pos maxima (LDS gt cache still live) ----
  for (int it = 0; it < 2; ++it) {
    const int a = xc * NTHR + t + it * (32 * NTHR);
    if (a >= AA) continue;  // no wave-collectives in this phase

    const int v = acc[b * AA + a];
    const int cntv = v >> 16;
    int assign = -1;
    float align_v = 0.0f;

    if (cntv > 0) {
      const float apx = anchor_points[a * 2 + 0];
      const float apy = anchor_points[a * 2 + 1];
      const float* pbp = pred_boxes + ((size_t)b * AA + a) * 4;
      const float p0 = pbp[0], p1 = pbp[1], p2 = pbp[2], p3 = pbp[3];
      const float a2 = (p2 - p0) * (p3 - p1);

      if (cntv == 1) {
        assign = v & 0xffff;
      } else {
        float best_iou = -1.0f;
        int best_j = 0;
        for (int j = 0; j < NBB; j++) {
          const float gx0 = sbox[j][0], gy0 = sbox[j][1];
          const float gx1 = sbox[j][2], gy1 = sbox[j][3];
          const float d = fminf(fminf(apx - gx0, apy - gy0),
                                fminf(gx1 - apx, gy1 - apy));
          float iou = 0.0f;
          if (svalid[j] && d > 1e-8f) {
            const float iw = fmaxf(fminf(gx1, p2) - fmaxf(gx0, p0), 0.0f);
            const float ih = fmaxf(fminf(gy1, p3) - fmaxf(gy0, p1), 0.0f);
            const float inter = iw * ih;
            const float a1 = (gx1 - gx0) * (gy1 - gy0);
            iou = fmaxf(inter / (a1 + a2 - inter + 1e-10f), 0.0f);
          }
          if (iou > best_iou) { best_iou = iou; best_j = j; }
        }
        assign = best_j;
      }

      const int j = assign;
      const float gx0 = sbox[j][0], gy0 = sbox[j][1];
      const float gx1 = sbox[j][2], gy1 = sbox[j][3];
      const float iw = fmaxf(fminf(gx1, p2) - fmaxf(gx0, p0), 0.0f);
      const float ih = fmaxf(fminf(gy1, p3) - fmaxf(gy0, p1), 0.0f);
      const float inter = iw * ih;
      const float a1 = (gx1 - gx0) * (gy1 - gy0);
      const float iou = fmaxf(inter / (a1 + a2 - inter + 1e-10f), 0.0f);
      const float s = pred_scores[((size_t)b * AA + a) * CC + scls[j]];
      const float i2 = iou * iou;
      align_v = s * i2 * i2 * i2;
      atomicMax(&posA[b * NBB + j], __float_as_int(align_v));
      atomicMax(&posI[b * NBB + j], __float_as_int(iou));
    }
    assign_ws[b * AA + a] = assign;
    align_ws[b * AA + a] = align_v;
  }
  gg.sync();

  // ---- P4: write the entire output (grid-stride over float4 chunks) ----
  for (int idx = bid * NTHR + t; idx < BB * AA * 20; idx += GRID * NTHR) {
    const int aidx = idx / 20;
    const int c = idx - aidx * 20;
    const int ob = aidx / AA;

    const int assign = assign_ws[aidx];
    const int j0 = (assign >= 0) ? assign : 0;
    const int g = ob * NBB + j0;
    int label = gt_labels[g];
    label = min(max(label, 0), 80);

    float* out_scores = out + (size_t)BB * AA * 5;
    float4 vv = make_float4(0.f, 0.f, 0.f, 0.f);
    if (assign >= 0 && c == (label >> 2)) {
      const float pa = __int_as_float(posA[ob * NBB + assign]);
      const float pi = __int_as_float(posI[ob * NBB + assign]);
      const float norm = align_ws[aidx] * pi / (pa + 1e-8f);
      ((float*)&vv)[label & 3] = norm;
    }
    reinterpret_cast<float4*>(out_scores)[(size_t)aidx * 20 + c] = vv;

    if (c == 0) {
      out[aidx] = (float)label;
      float* out_boxes = out + (size_t)BB * AA;
      out_boxes[(size_t)aidx * 4 + 0] = gt_boxes[g * 4 + 0];
      out_boxes[(size_t)aidx * 4 + 1] = gt_boxes[g * 4 + 1];
      out_boxes[(size_t)aidx * 4 + 2] = gt_boxes[g * 4 + 2];
      out_boxes[(size_t)aidx * 4 + 3] = gt_boxes[g * 4 + 3];
      out[(size_t)BB * AA * 85 + aidx] = (assign >= 0) ? 1.0f : 0.0f;
    }
  }
}

// ===========================================================================
extern "C" void kernel_launch(void* const* d_in, const int* in_sizes, int n_in,
                              void* d_out, int out_size, void* d_ws, size_t ws_size,
                              hipStream_t stream) {
  const float* pred_scores = (const float*)d_in[0];
  const float* pred_boxes = (const float*)d_in[1];
  const float* anchor_points = (const float*)d_in[2];
  const int* gt_labels = (const int*)d_in[3];
  const float* gt_boxes = (const float*)d_in[4];
  const int* gt_mask = (const int*)d_in[5];
  float* out = (float*)d_out;
  char* ws = (char*)d_ws;

  // workspace layout (bytes); cnt|posA|posI contiguous (zeroed in P0)
  const size_t sz_cand = (size_t)BB * NBB * MAXC * 8;  // 12.58 MB
  const size_t sz_acc = (size_t)BB * AA * 4;           // 1.075 MB
  const size_t off_cand = 0;
  const size_t off_cnt = off_cand + sz_cand;
  const size_t off_posA = off_cnt + (size_t)BB * NBB * CSTR * 4;  // 64 KB
  const size_t off_posI = off_posA + 4096;
  const size_t off_acc = off_posI + 4096;
  const size_t off_assign = off_acc + sz_acc;
  const size_t off_align = off_assign + sz_acc;

  unsigned long long* cand = (unsigned long long*)(ws + off_cand);
  int* cnt = (int*)(ws + off_cnt);
  int* posA = (int*)(ws + off_posA);
  int* posI = (int*)(ws + off_posI);
  int* acc = (int*)(ws + off_acc);
  int* assign_ws = (int*)(ws + off_assign);
  float* align_ws = (float*)(ws + off_align);

  void* args[] = {
      (void*)&pred_scores, (void*)&pred_boxes, (void*)&anchor_points,
      (void*)&gt_labels,   (void*)&gt_boxes,   (void*)&gt_mask,
      (void*)&out,         (void*)&cand,       (void*)&cnt,
      (void*)&posA,        (void*)&posI,       (void*)&acc,
      (void*)&assign_ws,   (void*)&align_ws};
  hipLaunchCooperativeKernel((const void*)fused_kernel, dim3(GRID), dim3(NTHR),
                             args, 0, stream);
}

// Round 9
// 79.393 us; speedup vs baseline: 5.4987x; 5.4987x over previous
//
#include <hip/hip_runtime.h>
#include <cstdint>
#include <cstddef>

#define BB 32
#define AA 8400
#define NBB 32
#define CC 80
#define TOPKN 10

// ===========================================================================
// K1: per (b,j) block. Enumerate ONLY anchors inside the gt box via the
// analytic 3-level grid structure (anchor = ((ix+0.5)s,(iy+0.5)s), bit-exact
// recompute of the reference's (arange+0.5)*s in f32), re-tested with the
// exact d>1e-8 condition. Block top-10 by key = align_bits<<32 | (8400-a)
// (descending u64 == descending align, tie -> smaller anchor index ==
// lax.top_k semantics). Writes top-10 anchor indices (-1 pad) + zeroes pos.
// ===========================================================================
__global__ __launch_bounds__(256) void gt_topk_kernel(
    const float* __restrict__ pred_scores, const float* __restrict__ pred_boxes,
    const int* __restrict__ gt_labels, const float* __restrict__ gt_boxes,
    const int* __restrict__ gt_mask,
    int* __restrict__ tk, int* __restrict__ posA, int* __restrict__ posI) {
  const int j = blockIdx.x, b = blockIdx.y, t = threadIdx.x;
  const int g = b * NBB + j;
  if (t == 0) { posA[g] = 0; posI[g] = 0; }  // owner-zeroed; K2 maxes later

  const float gx0 = gt_boxes[g * 4 + 0], gy0 = gt_boxes[g * 4 + 1];
  const float gx1 = gt_boxes[g * 4 + 2], gy1 = gt_boxes[g * 4 + 3];
  const int cls = gt_labels[g];
  const bool valid = (gt_mask[g] != 0);
  const float ga1 = (gx1 - gx0) * (gy1 - gy0);

  unsigned long long tkkey[TOPKN];
#pragma unroll
  for (int k = 0; k < TOPKN; k++) tkkey[k] = 0ull;

  if (valid) {
    const int strides[3] = {8, 16, 32};
    const int grids[3] = {80, 40, 20};
    const int offs[3] = {0, 6400, 8000};
    for (int lvl = 0; lvl < 3; lvl++) {
      const float s = (float)strides[lvl];
      const int n = grids[lvl], off = offs[lvl];
      int lx = max(0, (int)floorf(gx0 / s - 0.5f) - 1);
      int hx = min(n - 1, (int)ceilf(gx1 / s - 0.5f) + 1);
      int ly = max(0, (int)floorf(gy0 / s - 0.5f) - 1);
      int hy = min(n - 1, (int)ceilf(gy1 / s - 0.5f) + 1);
      if (hx < lx || hy < ly) continue;
      const int w = hx - lx + 1;
      const int m = w * (hy - ly + 1);
      for (int i = t; i < m; i += 256) {
        const int ix = lx + i % w;
        const int iy = ly + i / w;
        const float apx = ((float)ix + 0.5f) * s;
        const float apy = ((float)iy + 0.5f) * s;
        const float d = fminf(fminf(apx - gx0, apy - gy0),
                              fminf(gx1 - apx, gy1 - apy));
        if (!(d > 1e-8f)) continue;
        const int a = off + iy * n + ix;
        const float* pb = pred_boxes + ((size_t)b * AA + a) * 4;
        const float p0 = pb[0], p1 = pb[1], p2 = pb[2], p3 = pb[3];
        const float iw = fmaxf(fminf(gx1, p2) - fmaxf(gx0, p0), 0.0f);
        const float ih = fmaxf(fminf(gy1, p3) - fmaxf(gy0, p1), 0.0f);
        const float inter = iw * ih;
        const float a2 = (p2 - p0) * (p3 - p1);
        const float iou = fmaxf(inter / (ga1 + a2 - inter + 1e-10f), 0.0f);
        const float sc = pred_scores[((size_t)b * AA + a) * CC + cls];
        const float i2 = iou * iou;
        const float align_v = sc * i2 * i2 * i2;
        const unsigned long long key =
            ((unsigned long long)__float_as_uint(align_v) << 32) |
            (unsigned int)(AA - a);
        if (key > tkkey[TOPKN - 1]) {
          tkkey[TOPKN - 1] = key;
#pragma unroll
          for (int k = TOPKN - 1; k > 0; k--) {
            if (tkkey[k] > tkkey[k - 1]) {
              unsigned long long tmp = tkkey[k];
              tkkey[k] = tkkey[k - 1];
              tkkey[k - 1] = tmp;
            }
          }
        }
      }
    }
  }

  __shared__ unsigned long long s_key[256][TOPKN];
#pragma unroll
  for (int k = 0; k < TOPKN; k++) s_key[t][k] = tkkey[k];
  __syncthreads();

  for (int stride = 128; stride >= 1; stride >>= 1) {
    if (t < stride) {
      unsigned long long mk[TOPKN];
      int p = 0, q = 0;
#pragma unroll
      for (int k = 0; k < TOPKN; k++) {
        const unsigned long long k1 = s_key[t][p], k2 = s_key[t + stride][q];
        if (k1 >= k2) { mk[k] = k1; p++; } else { mk[k] = k2; q++; }
      }
#pragma unroll
      for (int k = 0; k < TOPKN; k++) s_key[t][k] = mk[k];
    }
    __syncthreads();
  }

  if (t < TOPKN) {
    const unsigned long long key = s_key[0][t];
    tk[g * TOPKN + t] = (key != 0ull) ? (AA - (int)(key & 0xffffffffu)) : -1;
  }
}

// ===========================================================================
// K2: per anchor. 32-gt loop: inside test + iou; membership = scan of the 10
// stored indices; cnt==1 -> member j, cnt>1 -> first-max argmax_j iou (over
// ALL valid-inside gts, matching reference). ONE score gather per assigned
// anchor. atomicMax pos_align/pos_iou (nonneg float as int bits).
// ===========================================================================
__global__ __launch_bounds__(256) void assign_kernel(
    const float* __restrict__ pred_scores, const float* __restrict__ pred_boxes,
    const float* __restrict__ anchor_points, const int* __restrict__ gt_labels,
    const float* __restrict__ gt_boxes, const int* __restrict__ gt_mask,
    const int* __restrict__ tk,
    int* __restrict__ assign_ws, float* __restrict__ align_ws,
    int* __restrict__ posA, int* __restrict__ posI) {
  const int b = blockIdx.y, t = threadIdx.x;
  const int a = blockIdx.x * 256 + t;

  __shared__ float sbox[NBB][4];
  __shared__ int scls[NBB];
  __shared__ int svalid[NBB];
  __shared__ int stk[NBB][TOPKN];

  if (t < NBB) {
    const int g = b * NBB + t;
    sbox[t][0] = gt_boxes[g * 4 + 0];
    sbox[t][1] = gt_boxes[g * 4 + 1];
    sbox[t][2] = gt_boxes[g * 4 + 2];
    sbox[t][3] = gt_boxes[g * 4 + 3];
    scls[t] = gt_labels[g];
    svalid[t] = (gt_mask[g] != 0) ? 1 : 0;
  }
  for (int i = t; i < NBB * TOPKN; i += 256)
    stk[i / TOPKN][i % TOPKN] = tk[b * NBB * TOPKN + i];
  __syncthreads();

  if (a >= AA) return;

  const float apx = anchor_points[a * 2 + 0];
  const float apy = anchor_points[a * 2 + 1];
  const float* pb = pred_boxes + ((size_t)b * AA + a) * 4;
  const float p0 = pb[0], p1 = pb[1], p2 = pb[2], p3 = pb[3];
  const float a2 = (p2 - p0) * (p3 - p1);

  int cnt = 0, memj = 0;
  float mem_iou = 0.0f;
  float best_iou = -1.0f;
  int best_j = 0;

  for (int j = 0; j < NBB; j++) {
    const float gx0 = sbox[j][0], gy0 = sbox[j][1];
    const float gx1 = sbox[j][2], gy1 = sbox[j][3];
    const float d = fminf(fminf(apx - gx0, apy - gy0),
                          fminf(gx1 - apx, gy1 - apy));
    const bool vin = svalid[j] && (d > 1e-8f);
    float iou = 0.0f;
    if (vin) {
      const float iw = fmaxf(fminf(gx1, p2) - fmaxf(gx0, p0), 0.0f);
      const float ih = fmaxf(fminf(gy1, p3) - fmaxf(gy0, p1), 0.0f);
      const float inter = iw * ih;
      const float a1 = (gx1 - gx0) * (gy1 - gy0);
      iou = fmaxf(inter / (a1 + a2 - inter + 1e-10f), 0.0f);
    }
    if (iou > best_iou) { best_iou = iou; best_j = j; }  // first-max
    if (vin) {
      bool member = false;
#pragma unroll
      for (int k = 0; k < TOPKN; k++) member = member || (stk[j][k] == a);
      if (member) { cnt++; memj = j; mem_iou = iou; }
    }
  }

  int assign = -1;
  float align_v = 0.0f;
  if (cnt > 0) {
    const int jj = (cnt == 1) ? memj : best_j;
    const float iou_f = (cnt == 1) ? mem_iou : best_iou;
    const float sc = pred_scores[((size_t)b * AA + a) * CC + scls[jj]];
    const float i2 = iou_f * iou_f;
    align_v = sc * i2 * i2 * i2;
    assign = jj;
    atomicMax(&posA[b * NBB + jj], __float_as_int(align_v));
    atomicMax(&posI[b * NBB + jj], __float_as_int(iou_f));
  }
  assign_ws[b * AA + a] = assign;
  align_ws[b * AA + a] = align_v;
}

// ===========================================================================
// K3: write the whole output. One thread per float4 chunk of the scores
// tensor (20/anchor); chunk-0 thread also writes label/box/fg.
// ===========================================================================
__global__ __launch_bounds__(256) void write_out_kernel(
    const int* __restrict__ gt_labels, const float* __restrict__ gt_boxes,
    const int* __restrict__ assign_in, const float* __restrict__ align_in,
    const int* __restrict__ posA, const int* __restrict__ posI,
    float* __restrict__ out) {
  const int idx = blockIdx.x * 256 + threadIdx.x;  // [0, BB*AA*20)
  const int aidx = idx / 20;
  const int c = idx - aidx * 20;
  const int b = aidx / AA;

  const int assign = assign_in[aidx];
  const int j0 = (assign >= 0) ? assign : 0;
  const int g = b * NBB + j0;
  int label = gt_labels[g];
  label = min(max(label, 0), 80);

  float* out_scores = out + (size_t)BB * AA * 5;
  float4 vv = make_float4(0.f, 0.f, 0.f, 0.f);
  if (assign >= 0 && c == (label >> 2)) {
    const float pa = __int_as_float(posA[b * NBB + assign]);
    const float pi = __int_as_float(posI[b * NBB + assign]);
    const float norm = align_in[aidx] * pi / (pa + 1e-8f);
    ((float*)&vv)[label & 3] = norm;
  }
  reinterpret_cast<float4*>(out_scores)[(size_t)aidx * 20 + c] = vv;

  if (c == 0) {
    out[aidx] = (float)label;
    float* out_boxes = out + (size_t)BB * AA;
    out_boxes[(size_t)aidx * 4 + 0] = gt_boxes[g * 4 + 0];
    out_boxes[(size_t)aidx * 4 + 1] = gt_boxes[g * 4 + 1];
    out_boxes[(size_t)aidx * 4 + 2] = gt_boxes[g * 4 + 2];
    out_boxes[(size_t)aidx * 4 + 3] = gt_boxes[g * 4 + 3];
    out[(size_t)BB * AA * 85 + aidx] = (assign >= 0) ? 1.0f : 0.0f;
  }
}

// ===========================================================================
extern "C" void kernel_launch(void* const* d_in, const int* in_sizes, int n_in,
                              void* d_out, int out_size, void* d_ws, size_t ws_size,
                              hipStream_t stream) {
  const float* pred_scores = (const float*)d_in[0];
  const float* pred_boxes = (const float*)d_in[1];
  const float* anchor_points = (const float*)d_in[2];
  const int* gt_labels = (const int*)d_in[3];
  const float* gt_boxes = (const float*)d_in[4];
  const int* gt_mask = (const int*)d_in[5];
  float* out = (float*)d_out;
  char* ws = (char*)d_ws;

  // workspace layout (bytes)
  const size_t sz_acc = (size_t)BB * AA * 4;               // 1.075 MB
  const size_t off_tk = 0;                                 // 1024*10*4 = 40KB
  const size_t off_posA = off_tk + (size_t)BB * NBB * TOPKN * 4;
  const size_t off_posI = off_posA + 4096;
  const size_t off_assign = off_posI + 4096;
  const size_t off_align = off_assign + sz_acc;

  int* tk = (int*)(ws + off_tk);
  int* posA = (int*)(ws + off_posA);
  int* posI = (int*)(ws + off_posI);
  int* assign_ws = (int*)(ws + off_assign);
  float* align_ws = (float*)(ws + off_align);

  dim3 g1(NBB, BB);
  gt_topk_kernel<<<g1, 256, 0, stream>>>(pred_scores, pred_boxes, gt_labels,
                                         gt_boxes, gt_mask, tk, posA, posI);

  dim3 g2((AA + 255) / 256, BB);
  assign_kernel<<<g2, 256, 0, stream>>>(pred_scores, pred_boxes, anchor_points,
                                        gt_labels, gt_boxes, gt_mask, tk,
                                        assign_ws, align_ws, posA, posI);

  const int nchunks = BB * AA * 20;
  write_out_kernel<<<(nchunks + 255) / 256, 256, 0, stream>>>(
      gt_labels, gt_boxes, assign_ws, align_ws, posA, posI, out);
}